// Round 8
// baseline (105.105 us; speedup 1.0000x reference)
//
#include <hip/hip_runtime.h>
#include <math.h>

#define N_ROWS 4096
#define DIM    256
#define P_SZ   5532
#define Q_SZ   5000
#define C_COLS 10532            // P+Q
#define TPAD   10624            // table rows padded to 83*128 (zero-filled)
#define PSTR   10624            // proj row stride in u16 elems == TPAD (full tiles)
#define NGR    (PSTR / 16)      // 1328 uint4 granules per proj row (16B = 8 elems)
#define K_SEL  701              // HARD_NUM + 1
#define SCALAR 30.0f
#define C2     (SCALAR * 1.4426950408889634f)   // log2(e)*30

typedef __attribute__((ext_vector_type(8))) short   short8;
typedef __attribute__((ext_vector_type(4))) float   float4_t;
typedef __attribute__((ext_vector_type(4))) unsigned short ushort4_t;
typedef __attribute__((ext_vector_type(8))) unsigned short ushort8_t;
typedef __attribute__((ext_vector_type(4))) unsigned int  uint4_t;

// ---------------- helpers ----------------
__device__ __forceinline__ unsigned short f2bf(float f) {   // fp32 -> bf16 RNE
    unsigned u = __float_as_uint(f);
    unsigned r = u + 0x7FFFu + ((u >> 16) & 1u);
    return (unsigned short)(r >> 16);
}
__device__ __forceinline__ float bf2f(unsigned short u) {
    return __uint_as_float((unsigned)u << 16);
}
__device__ __forceinline__ unsigned short key16(unsigned short u) { // order-preserving key
    return (u & 0x8000u) ? (unsigned short)(~u) : (unsigned short)(u | 0x8000u);
}
__device__ __forceinline__ float key2f16(unsigned key) {    // inverse: key -> float
    unsigned short b = (key & 0x8000u) ? (unsigned short)(key & 0x7FFFu)
                                       : (unsigned short)(~key & 0xFFFFu);
    return bf2f(b);
}
__device__ __forceinline__ void gload16(const void* g, void* l) {
    __builtin_amdgcn_global_load_lds(
        (const __attribute__((address_space(1))) unsigned int*)g,
        (__attribute__((address_space(3))) unsigned int*)l, 16, 0, 0);
}

// ---------------- fp32 -> bf16 pre-conversion (inputs + padded table) ----------------
#define NIN_G  (N_ROWS * DIM / 4)       // 262144 float4 granules
#define NTAB_G (TPAD * DIM / 4)         // 679936

__global__ __launch_bounds__(256) void convert_bf16(
    const float* __restrict__ inputs, const float* __restrict__ lut,
    const float* __restrict__ cq, unsigned short* __restrict__ in_bf,
    unsigned short* __restrict__ tab_bf)
{
    const int g = blockIdx.x * 256 + threadIdx.x;
    if (g >= NIN_G + NTAB_G) return;
    float4_t v;
    unsigned short* dst;
    if (g < NIN_G) {
        v = *(const float4_t*)&inputs[(size_t)g * 4];
        dst = in_bf + (size_t)g * 4;
    } else {
        const int t = g - NIN_G;
        const int row = t >> 6;                 // /(DIM/4)
        const int c4  = (t & 63) * 4;
        if (row < P_SZ)        v = *(const float4_t*)&lut[(size_t)row * DIM + c4];
        else if (row < C_COLS) v = *(const float4_t*)&cq[(size_t)(row - P_SZ) * DIM + c4];
        else                   v = (float4_t){0.f, 0.f, 0.f, 0.f};
        dst = tab_bf + (size_t)t * 4;
    }
    ushort4_t h = { f2bf(v.x), f2bf(v.y), f2bf(v.z), f2bf(v.w) };
    *(ushort4_t*)dst = h;
}

// ---------------- bf16 MFMA GEMM: proj(key16) = key16((in @ tab^T) * rel) ----------------
// double-buffered global_load_lds staging with counted vmcnt (T3/T4-lite)
#define NWG_X 83
#define NWG_Y 32
#define NWG   (NWG_X * NWG_Y)   // 2656, divisible by 8
#define CSTR  132               // C-tile LDS row stride in elems (264 B, conflict-free)

__global__ __launch_bounds__(256) void gemm_proj(
    const unsigned short* __restrict__ in_bf,
    const unsigned short* __restrict__ tab_bf,
    const float* __restrict__ rel,
    unsigned short* __restrict__ proj)
{
    // smem[0..1] = A buffers, smem[2..3] = B buffers (16 KB each, 64 KB total)
    // epilogue C-tile (128 x 264 B = 33792 B) aliases smem[0..2]
    __shared__ __align__(16) unsigned short smem[4][128 * 64];

    const int tid  = threadIdx.x;
    const int lane = tid & 63, wid = tid >> 6;
    const int wm = wid >> 1, wn = wid & 1;

    // XCD-bijective swizzle, col-major decode: each XCD chunk keeps full A in L2
    const int phys = blockIdx.x;
    const int wg   = (phys & 7) * (NWG / 8) + (phys >> 3);
    const int bx   = wg >> 5;               // 0..82 col-block
    const int by   = wg & 31;               // 0..31 row-block
    const int row0 = by * 128, col0 = bx * 128;

    float4_t acc[4][4];
    #pragma unroll
    for (int i = 0; i < 4; ++i)
        #pragma unroll
        for (int j = 0; j < 4; ++j)
            acc[i][j] = (float4_t){0.f, 0.f, 0.f, 0.f};

    // stage: linear LDS dest + inverse-swizzled global source (16B granules)
    auto STAGE = [&](int b, int k0) {
        #pragma unroll
        for (int it = 0; it < 4; ++it) {
            const int g  = it * 256 + tid;       // granule: LDS byte = g*16
            const int r  = g >> 3;               // 0..127
            const int kb = ((g & 7) * 16) ^ ((r & 7) << 4);   // src byte within row
            gload16(in_bf  + (size_t)(row0 + r) * DIM + k0 + (kb >> 1),
                    (char*)&smem[b][0] + g * 16);
            gload16(tab_bf + (size_t)(col0 + r) * DIM + k0 + (kb >> 1),
                    (char*)&smem[2 + b][0] + g * 16);
        }
    };

    STAGE(0, 0);                                  // prologue: tile 0 in flight (8/thread)
    #pragma unroll
    for (int t = 0; t < 4; ++t) {
        if (t < 3) {
            STAGE((t + 1) & 1, (t + 1) * 64);     // issue next tile (now 16 in flight)
            asm volatile("s_waitcnt vmcnt(8)" ::: "memory");   // current tile's 8 done
        } else {
            asm volatile("s_waitcnt vmcnt(0)" ::: "memory");
        }
        __builtin_amdgcn_s_barrier();             // every wave verified its own loads

        const char* At = (const char*)&smem[t & 1][0];
        const char* Bt = (const char*)&smem[2 + (t & 1)][0];
        #pragma unroll
        for (int kk = 0; kk < 2; ++kk) {
            const int krow = lane & 15;
            const int kb   = kk * 64 + ((lane >> 4) << 4);
            short8 af[4], bfr[4];
            #pragma unroll
            for (int i = 0; i < 4; ++i) {
                const int r = wm * 64 + i * 16 + krow;
                af[i] = *(const short8*)(At + (r * 128 + (kb ^ ((r & 7) << 4))));
            }
            #pragma unroll
            for (int j = 0; j < 4; ++j) {
                const int r = wn * 64 + j * 16 + krow;
                bfr[j] = *(const short8*)(Bt + (r * 128 + (kb ^ ((r & 7) << 4))));
            }
            #pragma unroll
            for (int i = 0; i < 4; ++i)
                #pragma unroll
                for (int j = 0; j < 4; ++j)
                    acc[i][j] = __builtin_amdgcn_mfma_f32_16x16x32_bf16(af[i], bfr[j], acc[i][j], 0, 0, 0);
        }
        __builtin_amdgcn_s_barrier();             // all reads of this buffer done
    }

    // epilogue: C layout col=lane&15, row=(lane>>4)*4+rr  [m89]
    // stage key16(bf16 C) in LDS (row stride CSTR), then coalesced 16B stores
    unsigned short* ctile = &smem[0][0];
    const int lr = (lane >> 4) << 2;
    const int lc = lane & 15;
    #pragma unroll
    for (int j = 0; j < 4; ++j) {
        const int cl  = wn * 64 + j * 16 + lc;        // tile-local col
        const int col = col0 + cl;
        const bool pad = (col >= C_COLS);
        const float rl = pad ? 0.f : rel[col];
        #pragma unroll
        for (int i = 0; i < 4; ++i) {
            const int rbase = wm * 64 + i * 16 + lr;  // tile-local row
            #pragma unroll
            for (int rr = 0; rr < 4; ++rr)
                ctile[(rbase + rr) * CSTR + cl] =
                    pad ? (unsigned short)0u : key16(f2bf(acc[i][j][rr] * rl));
        }
    }
    __syncthreads();
    // 128 rows x 256 B: granule g -> row g>>4, 16B chunk (g&15)
    #pragma unroll
    for (int it = 0; it < 8; ++it) {
        const int g = it * 256 + tid;
        const int r = g >> 4;
        const int c8 = (g & 15) * 8;                  // col in elems
        *(ushort8_t*)(proj + (size_t)(row0 + r) * PSTR + col0 + c8) =
            *(const ushort8_t*)&ctile[r * CSTR + c8];
    }
}

// ---------------- per-row: register-resident 2-pass radix select + masked LSE ----
// proj holds key16 (monotone). ONE global sweep: row -> 24 VGPRs (6 x uint4).
// Pass 1: 256-bin hist (key bits [15:8]), 32-way privatized (stride 257: bank =
// (copy+bin)%32 -> all copies of a bin in distinct banks; <=2 lanes/copy per wave).
// Pass 2 (regs): sub-hist low byte among boundary-bin elems. Pass 3 (regs):
// deterministic masked exp sweep. Count-only LDS atomics; no float atomics.
#define NCPY 32
__global__ __launch_bounds__(256) void row_loss_kernel(
    const unsigned short* __restrict__ proj, const int* __restrict__ labels,
    float* __restrict__ row_loss)
{
    __shared__ unsigned h1[NCPY * 257];   // 32896 B
    __shared__ unsigned h2[256];
    __shared__ unsigned wsum[4];
    __shared__ float    fsum[4];
    __shared__ unsigned sel_bin, sel_k, sel_sub;

    const int tid = threadIdx.x, lane = tid & 63, wid = tid >> 6;
    const int row = blockIdx.x;
    const uint4_t* prow = (const uint4_t*)(proj + (size_t)row * PSTR);
    const unsigned cbase = (unsigned)(tid & (NCPY - 1)) * 257;

    #pragma unroll
    for (int i = 0; i < NCPY * 257; i += 256)
        if (i + tid < NCPY * 257) h1[i + tid] = 0;
    h2[tid] = 0;
    __syncthreads();

    // ---- single global sweep: row into registers
    const int tailv = (1280 + tid < NGR);             // tid < 48
    uint4_t r0 = prow[tid];
    uint4_t r1 = prow[256 + tid];
    uint4_t r2 = prow[512 + tid];
    uint4_t r3 = prow[768 + tid];
    uint4_t r4 = prow[1024 + tid];
    uint4_t r5 = prow[tailv ? 1280 + tid : 1279];     // clamped (harmless re-read)

    // ---- pass 1: histogram on key bits [15:8], dword pair-combined
    auto HB = [&](unsigned w) {
        const unsigned bl = (w >> 8) & 0xFFu, bh = w >> 24;
        if (bl == bh) atomicAdd(&h1[cbase + bl], 2u);
        else { atomicAdd(&h1[cbase + bl], 1u); atomicAdd(&h1[cbase + bh], 1u); }
    };
    #pragma unroll
    for (int d = 0; d < 4; ++d) HB(r0[d]);
    #pragma unroll
    for (int d = 0; d < 4; ++d) HB(r1[d]);
    #pragma unroll
    for (int d = 0; d < 4; ++d) HB(r2[d]);
    #pragma unroll
    for (int d = 0; d < 4; ++d) HB(r3[d]);
    #pragma unroll
    for (int d = 0; d < 4; ++d) HB(r4[d]);
    if (tailv) {
        #pragma unroll
        for (int d = 0; d < 4; ++d) HB(r5[d]);
    }
    __syncthreads();

    // ---- scan 1: thread t owns bin t; suffix-from-top; find boundary bin
    {
        unsigned c = 0;
        #pragma unroll
        for (int cp = 0; cp < NCPY; ++cp) c += h1[cp * 257 + tid];
        unsigned incl = c;
        #pragma unroll
        for (int off = 1; off < 64; off <<= 1) {
            const unsigned t = __shfl_down(incl, off, 64);
            if (lane + off < 64) incl += t;
        }
        if (lane == 0) wsum[wid] = incl;
        __syncthreads();
        unsigned above = incl - c;
        for (int w = wid + 1; w < 4; ++w) above += wsum[w];
        if (above < K_SEL && above + c >= K_SEL) {
            sel_bin = (unsigned)tid; sel_k = K_SEL - above;
        }
    }
    __syncthreads();
    const unsigned b1 = sel_bin;
    const unsigned k2 = sel_k;
    __syncthreads();

    // ---- pass 2 (regs): sub-histogram (low byte) among bin-b1 elements
    auto SB = [&](unsigned w) {
        const unsigned lo = w & 0xFFFFu, hi = w >> 16;
        if ((lo >> 8) == b1) atomicAdd(&h2[lo & 0xFFu], 1u);
        if ((hi >> 8) == b1) atomicAdd(&h2[hi & 0xFFu], 1u);
    };
    #pragma unroll
    for (int d = 0; d < 4; ++d) SB(r0[d]);
    #pragma unroll
    for (int d = 0; d < 4; ++d) SB(r1[d]);
    #pragma unroll
    for (int d = 0; d < 4; ++d) SB(r2[d]);
    #pragma unroll
    for (int d = 0; d < 4; ++d) SB(r3[d]);
    #pragma unroll
    for (int d = 0; d < 4; ++d) SB(r4[d]);
    if (tailv) {
        #pragma unroll
        for (int d = 0; d < 4; ++d) SB(r5[d]);
    }
    __syncthreads();

    // ---- scan 2: find sub-bin -> exact boundary key
    {
        const unsigned c = h2[tid];
        unsigned incl = c;
        #pragma unroll
        for (int off = 1; off < 64; off <<= 1) {
            const unsigned t = __shfl_down(incl, off, 64);
            if (lane + off < 64) incl += t;
        }
        if (lane == 0) wsum[wid] = incl;
        __syncthreads();
        unsigned above = incl - c;
        for (int w = wid + 1; w < 4; ++w) above += wsum[w];
        if (above < k2 && above + c >= k2) sel_sub = (unsigned)tid;
    }
    __syncthreads();
    const unsigned bkey = (b1 << 8) | sel_sub;

    // ---- pass 3 (regs): masked exp sum (deterministic order)
    float s = 0.f;
    auto EX = [&](unsigned w) {
        const unsigned lo = w & 0xFFFFu, hi = w >> 16;
        if (lo >= bkey) s += exp2f(C2 * key2f16(lo) - C2);
        if (hi >= bkey) s += exp2f(C2 * key2f16(hi) - C2);
    };
    #pragma unroll
    for (int d = 0; d < 4; ++d) EX(r0[d]);
    #pragma unroll
    for (int d = 0; d < 4; ++d) EX(r1[d]);
    #pragma unroll
    for (int d = 0; d < 4; ++d) EX(r2[d]);
    #pragma unroll
    for (int d = 0; d < 4; ++d) EX(r3[d]);
    #pragma unroll
    for (int d = 0; d < 4; ++d) EX(r4[d]);
    if (tailv) {
        #pragma unroll
        for (int d = 0; d < 4; ++d) EX(r5[d]);
    }
    #pragma unroll
    for (int off = 1; off < 64; off <<= 1) {
        const float t = __shfl_down(s, off, 64);
        if (lane + off < 64) s += t;
    }
    if (lane == 0) fsum[wid] = s;
    __syncthreads();

    if (tid == 0) {
        float total = fsum[0] + fsum[1] + fsum[2] + fsum[3];
        const unsigned ulk = ((const unsigned short*)prow)[labels[row]];  // label < P_SZ
        const float pl = key2f16(ulk);
        if (ulk < bkey) total += exp2f(C2 * pl - C2);
        row_loss[row] = SCALAR * 1.0f + logf(total) - SCALAR * pl;
    }
}

// ---------------- final mean ----------------
__global__ __launch_bounds__(256) void final_reduce(
    const float* __restrict__ row_loss, float* __restrict__ out)
{
    __shared__ float fred[4];
    const int tid = threadIdx.x, lane = tid & 63, wid = tid >> 6;
    float s = 0.f;
    for (int i = tid; i < N_ROWS; i += 256) s += row_loss[i];
    #pragma unroll
    for (int off = 1; off < 64; off <<= 1) {
        const float t = __shfl_down(s, off, 64);
        if (lane + off < 64) s += t;
    }
    if (lane == 0) fred[wid] = s;
    __syncthreads();
    if (tid == 0) out[0] = (fred[0] + fred[1] + fred[2] + fred[3]) / (float)N_ROWS;
}

extern "C" void kernel_launch(void* const* d_in, const int* in_sizes, int n_in,
                              void* d_out, int out_size, void* d_ws, size_t ws_size,
                              hipStream_t stream) {
    const float* inputs = (const float*)d_in[0];
    const int*   labels = (const int*)d_in[1];
    const float* lut    = (const float*)d_in[2];
    const float* cq     = (const float*)d_in[3];
    const float* rel    = (const float*)d_in[4];
    float* out = (float*)d_out;

    // ws: in_bf [4096*256] | tab_bf [10624*256] | proj [4096*10624] u16 | row_loss
    unsigned short* in_bf  = (unsigned short*)d_ws;
    unsigned short* tab_bf = in_bf  + (size_t)N_ROWS * DIM;
    unsigned short* proj   = tab_bf + (size_t)TPAD * DIM;
    float* rl_buf = (float*)(proj + (size_t)N_ROWS * PSTR);

    convert_bf16<<<(NIN_G + NTAB_G) / 256, 256, 0, stream>>>(inputs, lut, cq, in_bf, tab_bf);
    gemm_proj<<<NWG, 256, 0, stream>>>(in_bf, tab_bf, rel, proj);
    row_loss_kernel<<<N_ROWS, 256, 0, stream>>>(proj, labels, rl_buf);
    final_reduce<<<1, 256, 0, stream>>>(rl_buf, out);
}

// Round 9
// 100.164 us; speedup vs baseline: 1.0493x; 1.0493x over previous
//
#include <hip/hip_runtime.h>
#include <math.h>

#define N_ROWS 4096
#define DIM    256
#define P_SZ   5532
#define Q_SZ   5000
#define C_COLS 10532            // P+Q
#define TPAD   10624            // table rows padded to 83*128 (zero-filled)
#define PSTR   10624            // proj row stride in u16 elems == TPAD (full tiles)
#define NGR    (PSTR / 16)      // 1328 uint4 granules per proj row (16B = 8 elems)
#define K_SEL  701              // HARD_NUM + 1
#define SCALAR 30.0f
#define C2     (SCALAR * 1.4426950408889634f)   // log2(e)*30

typedef __attribute__((ext_vector_type(8))) short   short8;
typedef __attribute__((ext_vector_type(4))) float   float4_t;
typedef __attribute__((ext_vector_type(4))) unsigned short ushort4_t;
typedef __attribute__((ext_vector_type(8))) unsigned short ushort8_t;
typedef __attribute__((ext_vector_type(4))) unsigned int  uint4_t;

// ---------------- helpers ----------------
__device__ __forceinline__ unsigned short f2bf(float f) {   // fp32 -> bf16 RNE
    unsigned u = __float_as_uint(f);
    unsigned r = u + 0x7FFFu + ((u >> 16) & 1u);
    return (unsigned short)(r >> 16);
}
__device__ __forceinline__ float bf2f(unsigned short u) {
    return __uint_as_float((unsigned)u << 16);
}
__device__ __forceinline__ unsigned short key16(unsigned short u) { // order-preserving key
    return (u & 0x8000u) ? (unsigned short)(~u) : (unsigned short)(u | 0x8000u);
}
__device__ __forceinline__ float key2f16(unsigned key) {    // inverse: key -> float
    unsigned short b = (key & 0x8000u) ? (unsigned short)(key & 0x7FFFu)
                                       : (unsigned short)(~key & 0xFFFFu);
    return bf2f(b);
}
__device__ __forceinline__ void gload16(const void* g, void* l) {
    __builtin_amdgcn_global_load_lds(
        (const __attribute__((address_space(1))) unsigned int*)g,
        (__attribute__((address_space(3))) unsigned int*)l, 16, 0, 0);
}

// ---------------- fp32 -> bf16 pre-conversion (inputs + padded table) ----------------
#define NIN_G  (N_ROWS * DIM / 4)       // 262144 float4 granules
#define NTAB_G (TPAD * DIM / 4)         // 679936

__global__ __launch_bounds__(256) void convert_bf16(
    const float* __restrict__ inputs, const float* __restrict__ lut,
    const float* __restrict__ cq, unsigned short* __restrict__ in_bf,
    unsigned short* __restrict__ tab_bf)
{
    const int g = blockIdx.x * 256 + threadIdx.x;
    if (g >= NIN_G + NTAB_G) return;
    float4_t v;
    unsigned short* dst;
    if (g < NIN_G) {
        v = *(const float4_t*)&inputs[(size_t)g * 4];
        dst = in_bf + (size_t)g * 4;
    } else {
        const int t = g - NIN_G;
        const int row = t >> 6;                 // /(DIM/4)
        const int c4  = (t & 63) * 4;
        if (row < P_SZ)        v = *(const float4_t*)&lut[(size_t)row * DIM + c4];
        else if (row < C_COLS) v = *(const float4_t*)&cq[(size_t)(row - P_SZ) * DIM + c4];
        else                   v = (float4_t){0.f, 0.f, 0.f, 0.f};
        dst = tab_bf + (size_t)t * 4;
    }
    ushort4_t h = { f2bf(v.x), f2bf(v.y), f2bf(v.z), f2bf(v.w) };
    *(ushort4_t*)dst = h;
}

// ---------------- bf16 MFMA GEMM: proj(key16) = key16((in @ tab^T) * rel) ----------------
// R6 structure (single-buffer, 33792 B LDS union) — R7's 64KB dbuf cut occupancy and lost
#define NWG_X 83
#define NWG_Y 32
#define NWG   (NWG_X * NWG_Y)   // 2656, divisible by 8
#define CSTR  132               // C-tile LDS row stride in elems (264 B, conflict-free)

__global__ __launch_bounds__(256) void gemm_proj(
    const unsigned short* __restrict__ in_bf,
    const unsigned short* __restrict__ tab_bf,
    const float* __restrict__ rel,
    unsigned short* __restrict__ proj)
{
    // union: K-loop stage tiles (2 x 16 KB) / epilogue C-tile (128 x 264 B)
    __shared__ __align__(16) unsigned short smem[128 * CSTR];   // 33792 B
    unsigned short* At = smem;                 // elem (r,k) at byte r*128 + ((k*2)^((r&7)<<4))
    unsigned short* Bt = smem + 128 * 64;

    const int tid  = threadIdx.x;
    const int lane = tid & 63, wid = tid >> 6;
    const int wm = wid >> 1, wn = wid & 1;

    // XCD-bijective swizzle, col-major decode: each XCD chunk keeps full A in L2
    const int phys = blockIdx.x;
    const int wg   = (phys & 7) * (NWG / 8) + (phys >> 3);
    const int bx   = wg >> 5;               // 0..82 col-block
    const int by   = wg & 31;               // 0..31 row-block
    const int row0 = by * 128, col0 = bx * 128;

    float4_t acc[4][4];
    #pragma unroll
    for (int i = 0; i < 4; ++i)
        #pragma unroll
        for (int j = 0; j < 4; ++j)
            acc[i][j] = (float4_t){0.f, 0.f, 0.f, 0.f};

    for (int k0 = 0; k0 < DIM; k0 += 64) {
        // stage: linear LDS dest + inverse-swizzled global source (16B granules)
        #pragma unroll
        for (int it = 0; it < 4; ++it) {
            const int g  = it * 256 + tid;       // granule: LDS byte = g*16
            const int r  = g >> 3;               // 0..127
            const int kb = ((g & 7) * 16) ^ ((r & 7) << 4);   // src byte within row
            gload16(in_bf  + (size_t)(row0 + r) * DIM + k0 + (kb >> 1),
                    (char*)At + g * 16);
            gload16(tab_bf + (size_t)(col0 + r) * DIM + k0 + (kb >> 1),
                    (char*)Bt + g * 16);
        }
        __syncthreads();

        #pragma unroll
        for (int kk = 0; kk < 2; ++kk) {
            const int krow = lane & 15;
            const int kb   = kk * 64 + ((lane >> 4) << 4);
            short8 af[4], bfr[4];
            #pragma unroll
            for (int i = 0; i < 4; ++i) {
                const int r = wm * 64 + i * 16 + krow;
                af[i] = *(const short8*)((const char*)At + (r * 128 + (kb ^ ((r & 7) << 4))));
            }
            #pragma unroll
            for (int j = 0; j < 4; ++j) {
                const int r = wn * 64 + j * 16 + krow;
                bfr[j] = *(const short8*)((const char*)Bt + (r * 128 + (kb ^ ((r & 7) << 4))));
            }
            #pragma unroll
            for (int i = 0; i < 4; ++i)
                #pragma unroll
                for (int j = 0; j < 4; ++j)
                    acc[i][j] = __builtin_amdgcn_mfma_f32_16x16x32_bf16(af[i], bfr[j], acc[i][j], 0, 0, 0);
        }
        __syncthreads();
    }

    // epilogue: C layout col=lane&15, row=(lane>>4)*4+rr  [m89]
    // stage key16(bf16 C) in LDS (row stride CSTR), then coalesced 16B stores
    const int lr = (lane >> 4) << 2;
    const int lc = lane & 15;
    #pragma unroll
    for (int j = 0; j < 4; ++j) {
        const int cl  = wn * 64 + j * 16 + lc;        // tile-local col
        const int col = col0 + cl;
        const bool pad = (col >= C_COLS);
        const float rl = pad ? 0.f : rel[col];
        #pragma unroll
        for (int i = 0; i < 4; ++i) {
            const int rbase = wm * 64 + i * 16 + lr;  // tile-local row
            #pragma unroll
            for (int rr = 0; rr < 4; ++rr)
                smem[(rbase + rr) * CSTR + cl] =
                    pad ? (unsigned short)0u : key16(f2bf(acc[i][j][rr] * rl));
        }
    }
    __syncthreads();
    // 128 rows x 256 B: granule g -> row g>>4, 16B chunk (g&15)
    #pragma unroll
    for (int it = 0; it < 8; ++it) {
        const int g = it * 256 + tid;
        const int r = g >> 4;
        const int c8 = (g & 15) * 8;                  // col in elems
        *(ushort8_t*)(proj + (size_t)(row0 + r) * PSTR + col0 + c8) =
            *(const ushort8_t*)&smem[r * CSTR + c8];
    }
}

// ---------------- per-row: radix select + stash-compacted masked LSE ----------------
// proj holds key16 (monotone). One global sweep into registers. Pass 1: 256-bin
// count hist (16-way privatized, stride 257). Scan 1 -> boundary bin b1. Sweep 2
// (registers): stash keys >= b1<<8 into per-thread lane-major LDS slots (no
// atomics). h2 sub-hist + exp sum run over the compact stash only (~1-4K elems).
// Per-thread cap 32 with exact register-resweep fallback. Deterministic.
#define NCPY  16
#define SCAP  32
__global__ __launch_bounds__(256) void row_loss_kernel(
    const unsigned short* __restrict__ proj, const int* __restrict__ labels,
    float* __restrict__ row_loss)
{
    __shared__ unsigned h1[NCPY * 257];          // 16448 B
    __shared__ unsigned short stash[SCAP * 256]; // 16384 B, lane-major
    __shared__ unsigned h2[256];                 // 1024 B
    __shared__ unsigned wsum[4];
    __shared__ float    fsum[4];
    __shared__ unsigned sel_bin, sel_k, sel_sub, ovf;

    const int tid = threadIdx.x, lane = tid & 63, wid = tid >> 6;
    const int row = blockIdx.x;
    const uint4_t* prow = (const uint4_t*)(proj + (size_t)row * PSTR);
    const unsigned cbase = (unsigned)(tid & (NCPY - 1)) * 257;

    for (int i = tid; i < NCPY * 257; i += 256) h1[i] = 0;
    h2[tid] = 0;
    if (tid == 0) ovf = 0;
    __syncthreads();

    // ---- single global sweep: row into registers
    const int tailv = (1280 + tid < NGR);             // tid < 48
    uint4_t r0 = prow[tid];
    uint4_t r1 = prow[256 + tid];
    uint4_t r2 = prow[512 + tid];
    uint4_t r3 = prow[768 + tid];
    uint4_t r4 = prow[1024 + tid];
    uint4_t r5 = prow[tailv ? 1280 + tid : 1279];     // clamped (guarded below)

    // ---- pass 1: count histogram on key bits [15:8]
    auto HB = [&](unsigned w) {
        atomicAdd(&h1[cbase + ((w >> 8) & 0xFFu)], 1u);
        atomicAdd(&h1[cbase + (w >> 24)], 1u);
    };
    #pragma unroll
    for (int d = 0; d < 4; ++d) HB(r0[d]);
    #pragma unroll
    for (int d = 0; d < 4; ++d) HB(r1[d]);
    #pragma unroll
    for (int d = 0; d < 4; ++d) HB(r2[d]);
    #pragma unroll
    for (int d = 0; d < 4; ++d) HB(r3[d]);
    #pragma unroll
    for (int d = 0; d < 4; ++d) HB(r4[d]);
    if (tailv) {
        #pragma unroll
        for (int d = 0; d < 4; ++d) HB(r5[d]);
    }
    __syncthreads();

    // ---- scan 1: thread t owns bin t; suffix-from-top; find boundary bin
    {
        unsigned c = 0;
        #pragma unroll
        for (int cp = 0; cp < NCPY; ++cp) c += h1[cp * 257 + tid];
        unsigned incl = c;
        #pragma unroll
        for (int off = 1; off < 64; off <<= 1) {
            const unsigned t = __shfl_down(incl, off, 64);
            if (lane + off < 64) incl += t;
        }
        if (lane == 0) wsum[wid] = incl;
        __syncthreads();
        unsigned above = incl - c;
        for (int w = wid + 1; w < 4; ++w) above += wsum[w];
        if (above < K_SEL && above + c >= K_SEL) {
            sel_bin = (unsigned)tid; sel_k = K_SEL - above;
        }
    }
    __syncthreads();
    const unsigned b1 = sel_bin;
    const unsigned k2 = sel_k;
    const unsigned kfloor = b1 << 8;                  // all keys >= kfloor are candidates
    __syncthreads();

    // ---- sweep 2 (regs): stash candidate keys, per-thread slots (lane-major)
    unsigned cnt = 0;
    auto ST = [&](unsigned key) {
        if (key >= kfloor) {
            if (cnt < SCAP) stash[cnt * 256 + tid] = (unsigned short)key;
            else ovf = 1u;
            ++cnt;
        }
    };
    auto SW = [&](uint4_t w) {
        #pragma unroll
        for (int d = 0; d < 4; ++d) { ST(w[d] & 0xFFFFu); ST(w[d] >> 16); }
    };
    SW(r0); SW(r1); SW(r2); SW(r3); SW(r4);
    if (tailv) SW(r5);
    __syncthreads();

    float s = 0.f;
    unsigned bkey;
    if (ovf == 0) {
        // ---- h2 sub-hist from stash (bin == b1 only)
        const unsigned kceil = kfloor + 256u;
        for (unsigned c = 0; c < cnt; ++c) {
            const unsigned key = stash[c * 256 + tid];
            if (key < kceil) atomicAdd(&h2[key & 0xFFu], 1u);
        }
        __syncthreads();
        // ---- scan 2: find sub-bin -> exact boundary key
        {
            const unsigned c = h2[tid];
            unsigned incl = c;
            #pragma unroll
            for (int off = 1; off < 64; off <<= 1) {
                const unsigned t = __shfl_down(incl, off, 64);
                if (lane + off < 64) incl += t;
            }
            if (lane == 0) wsum[wid] = incl;
            __syncthreads();
            unsigned above = incl - c;
            for (int w = wid + 1; w < 4; ++w) above += wsum[w];
            if (above < k2 && above + c >= k2) sel_sub = (unsigned)tid;
        }
        __syncthreads();
        bkey = kfloor | sel_sub;
        // ---- exp sum over stash (deterministic per-thread order)
        for (unsigned c = 0; c < cnt; ++c) {
            const unsigned key = stash[c * 256 + tid];
            if (key >= bkey) s += exp2f(C2 * key2f16(key) - C2);
        }
    } else {
        // ---- fallback (exact, rare): register re-sweeps as in R7
        auto SB = [&](unsigned w) {
            const unsigned lo = w & 0xFFFFu, hi = w >> 16;
            if ((lo >> 8) == b1) atomicAdd(&h2[lo & 0xFFu], 1u);
            if ((hi >> 8) == b1) atomicAdd(&h2[hi & 0xFFu], 1u);
        };
        SB(r0[0]); SB(r0[1]); SB(r0[2]); SB(r0[3]);
        SB(r1[0]); SB(r1[1]); SB(r1[2]); SB(r1[3]);
        SB(r2[0]); SB(r2[1]); SB(r2[2]); SB(r2[3]);
        SB(r3[0]); SB(r3[1]); SB(r3[2]); SB(r3[3]);
        SB(r4[0]); SB(r4[1]); SB(r4[2]); SB(r4[3]);
        if (tailv) { SB(r5[0]); SB(r5[1]); SB(r5[2]); SB(r5[3]); }
        __syncthreads();
        {
            const unsigned c = h2[tid];
            unsigned incl = c;
            #pragma unroll
            for (int off = 1; off < 64; off <<= 1) {
                const unsigned t = __shfl_down(incl, off, 64);
                if (lane + off < 64) incl += t;
            }
            if (lane == 0) wsum[wid] = incl;
            __syncthreads();
            unsigned above = incl - c;
            for (int w = wid + 1; w < 4; ++w) above += wsum[w];
            if (above < k2 && above + c >= k2) sel_sub = (unsigned)tid;
        }
        __syncthreads();
        bkey = kfloor | sel_sub;
        auto EX = [&](unsigned w) {
            const unsigned lo = w & 0xFFFFu, hi = w >> 16;
            if (lo >= bkey) s += exp2f(C2 * key2f16(lo) - C2);
            if (hi >= bkey) s += exp2f(C2 * key2f16(hi) - C2);
        };
        EX(r0[0]); EX(r0[1]); EX(r0[2]); EX(r0[3]);
        EX(r1[0]); EX(r1[1]); EX(r1[2]); EX(r1[3]);
        EX(r2[0]); EX(r2[1]); EX(r2[2]); EX(r2[3]);
        EX(r3[0]); EX(r3[1]); EX(r3[2]); EX(r3[3]);
        EX(r4[0]); EX(r4[1]); EX(r4[2]); EX(r4[3]);
        if (tailv) { EX(r5[0]); EX(r5[1]); EX(r5[2]); EX(r5[3]); }
    }

    // ---- block reduce + finish
    #pragma unroll
    for (int off = 1; off < 64; off <<= 1) {
        const float t = __shfl_down(s, off, 64);
        if (lane + off < 64) s += t;
    }
    if (lane == 0) fsum[wid] = s;
    __syncthreads();

    if (tid == 0) {
        float total = fsum[0] + fsum[1] + fsum[2] + fsum[3];
        const unsigned ulk = ((const unsigned short*)prow)[labels[row]];  // label < P_SZ
        const float pl = key2f16(ulk);
        if (ulk < bkey) total += exp2f(C2 * pl - C2);
        row_loss[row] = SCALAR * 1.0f + logf(total) - SCALAR * pl;
    }
}

// ---------------- final mean ----------------
__global__ __launch_bounds__(256) void final_reduce(
    const float* __restrict__ row_loss, float* __restrict__ out)
{
    __shared__ float fred[4];
    const int tid = threadIdx.x, lane = tid & 63, wid = tid >> 6;
    float s = 0.f;
    for (int i = tid; i < N_ROWS; i += 256) s += row_loss[i];
    #pragma unroll
    for (int off = 1; off < 64; off <<= 1) {
        const float t = __shfl_down(s, off, 64);
        if (lane + off < 64) s += t;
    }
    if (lane == 0) fred[wid] = s;
    __syncthreads();
    if (tid == 0) out[0] = (fred[0] + fred[1] + fred[2] + fred[3]) / (float)N_ROWS;
}

extern "C" void kernel_launch(void* const* d_in, const int* in_sizes, int n_in,
                              void* d_out, int out_size, void* d_ws, size_t ws_size,
                              hipStream_t stream) {
    const float* inputs = (const float*)d_in[0];
    const int*   labels = (const int*)d_in[1];
    const float* lut    = (const float*)d_in[2];
    const float* cq     = (const float*)d_in[3];
    const float* rel    = (const float*)d_in[4];
    float* out = (float*)d_out;

    // ws: in_bf [4096*256] | tab_bf [10624*256] | proj [4096*10624] u16 | row_loss
    unsigned short* in_bf  = (unsigned short*)d_ws;
    unsigned short* tab_bf = in_bf  + (size_t)N_ROWS * DIM;
    unsigned short* proj   = tab_bf + (size_t)TPAD * DIM;
    float* rl_buf = (float*)(proj + (size_t)N_ROWS * PSTR);

    convert_bf16<<<(NIN_G + NTAB_G) / 256, 256, 0, stream>>>(inputs, lut, cq, in_bf, tab_bf);
    gemm_proj<<<NWG, 256, 0, stream>>>(in_bf, tab_bf, rel, proj);
    row_loss_kernel<<<N_ROWS, 256, 0, stream>>>(proj, labels, rl_buf);
    final_reduce<<<1, 256, 0, stream>>>(rl_buf, out);
}